// Round 11
// baseline (53.923 us; speedup 1.0000x reference)
//
#include <hip/hip_runtime.h>

#define BATCH 32
#define LSEQ 4096
#define HDIM 512
#define PARTS 4

typedef float f32x4 __attribute__((ext_vector_type(4)));

// -----------------------------------------------------------------------------
// Kernel 1: partial projection. grid (BATCH, PARTS), block 512.
// vpart[p][b][h] = sum_{o in slice p} h_last[b][o] * W[o][h]
// (bias dropped: softmax cancels per-row constants)
// -----------------------------------------------------------------------------
__global__ __launch_bounds__(512) void proj_kernel(
    const float* __restrict__ hidden, const float* __restrict__ W,
    float* __restrict__ vpart)
{
    const int b    = blockIdx.x;
    const int part = blockIdx.y;
    const int h    = threadIdx.x;
    const int OS   = HDIM / PARTS;          // 128
    const int obase = part * OS;

    __shared__ float s_hl[HDIM / PARTS];
    if (h < OS) s_hl[h] = hidden[(BATCH + b) * HDIM + obase + h];
    __syncthreads();

    float acc = 0.f;
#pragma unroll 16
    for (int o = 0; o < OS; ++o) {
        acc += s_hl[o] * W[(obase + o) * HDIM + h];
    }
    vpart[(part * BATCH + b) * HDIM + h] = acc;
}

// -----------------------------------------------------------------------------
// Kernel 2: energies[b,l] = enc[b,l,:] . v[b,:]
// 16 lanes per row; 16 rows/wave; 64 rows/block; grid 2048.
// __launch_bounds__(256,6): cap VGPR ~85 (fits: vv 32 + e 32 + ~12 misc)
// -> 24 waves/CU resident, all 8 loads (128B/lane) in flight.
// -----------------------------------------------------------------------------
__global__ __launch_bounds__(256, 6) void energy_kernel(
    const float* __restrict__ enc, const float* __restrict__ vpart,
    float* __restrict__ energies)
{
    const int wave = threadIdx.x >> 6;
    const int lane = threadIdx.x & 63;
    const int sub  = lane >> 4;
    const int sl   = lane & 15;

    const int b      = blockIdx.x >> 6;            // 64 blocks per batch row
    const int l_base = (blockIdx.x & 63) * 64 + wave * 16;

    // hoist v = sum of 4 partials (L2-resident)
    const f32x4* vp0 = (const f32x4*)(vpart + (0 * BATCH + b) * HDIM);
    const f32x4* vp1 = (const f32x4*)(vpart + (1 * BATCH + b) * HDIM);
    const f32x4* vp2 = (const f32x4*)(vpart + (2 * BATCH + b) * HDIM);
    const f32x4* vp3 = (const f32x4*)(vpart + (3 * BATCH + b) * HDIM);
    f32x4 vv[8];
#pragma unroll
    for (int k = 0; k < 8; ++k) {
        const int ch = sl + 16 * k;
        vv[k] = vp0[ch] + vp1[ch] + vp2[ch] + vp3[ch];
    }

    const long rbase = (long)b * LSEQ + l_base;

#pragma unroll
    for (int batch = 0; batch < 4; ++batch) {
        const long r = rbase + batch * 4 + sub;
        const f32x4* ep = (const f32x4*)(enc + r * HDIM) + sl;

        f32x4 e[8];
#pragma unroll
        for (int k = 0; k < 8; ++k)
            e[k] = ep[16 * k];

        float d0 = e[0].x * vv[0].x + e[0].y * vv[0].y
                 + e[0].z * vv[0].z + e[0].w * vv[0].w;
        float d1 = e[1].x * vv[1].x + e[1].y * vv[1].y
                 + e[1].z * vv[1].z + e[1].w * vv[1].w;
        float d2 = e[2].x * vv[2].x + e[2].y * vv[2].y
                 + e[2].z * vv[2].z + e[2].w * vv[2].w;
        float d3 = e[3].x * vv[3].x + e[3].y * vv[3].y
                 + e[3].z * vv[3].z + e[3].w * vv[3].w;
        d0 += e[4].x * vv[4].x + e[4].y * vv[4].y
            + e[4].z * vv[4].z + e[4].w * vv[4].w;
        d1 += e[5].x * vv[5].x + e[5].y * vv[5].y
            + e[5].z * vv[5].z + e[5].w * vv[5].w;
        d2 += e[6].x * vv[6].x + e[6].y * vv[6].y
            + e[6].z * vv[6].z + e[6].w * vv[6].w;
        d3 += e[7].x * vv[7].x + e[7].y * vv[7].y
            + e[7].z * vv[7].z + e[7].w * vv[7].w;
        float d = (d0 + d1) + (d2 + d3);

        d += __shfl_xor(d, 1, 64);
        d += __shfl_xor(d, 2, 64);
        d += __shfl_xor(d, 4, 64);
        d += __shfl_xor(d, 8, 64);

        if (sl == 0) energies[r] = d;
    }
}

// -----------------------------------------------------------------------------
// Kernel 3: softmax over L per batch row, in place. 32 blocks x 1024 threads.
// -----------------------------------------------------------------------------
__global__ __launch_bounds__(1024) void softmax_kernel(float* __restrict__ out)
{
    const int b = blockIdx.x;
    const int t = threadIdx.x;
    const int wid  = t >> 6;
    const int lane = t & 63;

    float4* o4 = (float4*)(out + (long)b * LSEQ);

    float4 v0 = o4[t];
    float m = fmaxf(fmaxf(v0.x, v0.y), fmaxf(v0.z, v0.w));

    __shared__ float smax[16];
#pragma unroll
    for (int off = 1; off < 64; off <<= 1) m = fmaxf(m, __shfl_xor(m, off, 64));
    if (lane == 0) smax[wid] = m;
    __syncthreads();
#pragma unroll
    for (int w = 0; w < 16; ++w) m = fmaxf(m, smax[w]);

    v0.x = __expf(v0.x - m); v0.y = __expf(v0.y - m);
    v0.z = __expf(v0.z - m); v0.w = __expf(v0.w - m);

    float s = v0.x + v0.y + v0.z + v0.w;
    __shared__ float ssum[16];
#pragma unroll
    for (int off = 1; off < 64; off <<= 1) s += __shfl_xor(s, off, 64);
    if (lane == 0) ssum[wid] = s;
    __syncthreads();
    s = 0.f;
#pragma unroll
    for (int w = 0; w < 16; ++w) s += ssum[w];

    const float inv = 1.0f / s;
    v0.x *= inv; v0.y *= inv; v0.z *= inv; v0.w *= inv;
    o4[t] = v0;
}

// -----------------------------------------------------------------------------
extern "C" void kernel_launch(void* const* d_in, const int* in_sizes, int n_in,
                              void* d_out, int out_size, void* d_ws, size_t ws_size,
                              hipStream_t stream)
{
    const float* hidden = (const float*)d_in[0];   // (2,2,B,H)
    const float* enc    = (const float*)d_in[1];   // (B,L,H)
    const float* W      = (const float*)d_in[2];   // (H,H)

    float* ws    = (float*)d_ws;
    float* vpart = ws;                               // PARTS*B*H floats

    float* out = (float*)d_out;                      // B*L floats

    proj_kernel<<<dim3(BATCH, PARTS), 512, 0, stream>>>(hidden, W, vpart);
    energy_kernel<<<(BATCH * LSEQ) / 64, 256, 0, stream>>>(enc, vpart, out);
    softmax_kernel<<<BATCH, 1024, 0, stream>>>(out);
}